// Round 9
// baseline (130.541 us; speedup 1.0000x reference)
//
#include <hip/hip_runtime.h>

constexpr int IN_DIM  = 256;
constexpr int OUT_DIM = 64;
constexpr int NPB     = 128;          // nodes per bucket (dst >> 7)
constexpr int IPT     = 16;           // edges per thread in part_k

typedef __attribute__((ext_vector_type(8))) short bf16x8;
typedef __attribute__((ext_vector_type(4))) float f32x4;

// ---- K1: W fragment precompute + zero cnt[] (replaces hipMemsetAsync) ------
__global__ __launch_bounds__(64) void wfrag_k(const float* __restrict__ W,
                                              bf16x8* __restrict__ fragH,
                                              bf16x8* __restrict__ fragL,
                                              int* __restrict__ cnt) {
    const int gid = blockIdx.x * 64 + threadIdx.x;
    if (gid < 1024) cnt[gid] = 0;               // 32 blocks x 64 >= 1024

    const int kt = blockIdx.x >> 2;
    const int nt = blockIdx.x & 3;
    const int l  = threadIdx.x;
    const int col = nt * 16 + (l & 15);
    const int k0  = kt * 32 + (l >> 4) * 8;
    bf16x8 h, lo;
#pragma unroll
    for (int j = 0; j < 8; ++j) {
        float f = W[(size_t)(k0 + j) * OUT_DIM + col];
        unsigned u = __float_as_uint(f);
        h[j] = (short)(u >> 16);
        float r = f - __uint_as_float(u & 0xFFFF0000u);
        lo[j] = (short)(__float_as_uint(r) >> 16);
    }
    fragH[blockIdx.x * 64 + l] = h;
    fragL[blockIdx.x * 64 + l] = lo;
}

// ---- K2: union kernel — blocks [0,GB) = MFMA GEMM, [GB,GB+HB) = histogram --
// launch_bounds (256,2): VGPR budget ~256 so all 32 x-loads stay in flight.
__global__ __launch_bounds__(256, 2) void gemm_hist_k(
        const float* __restrict__ x,
        const bf16x8* __restrict__ fragH, const bf16x8* __restrict__ fragL,
        unsigned short* __restrict__ xw,
        const int* __restrict__ edst, int* __restrict__ cnt,
        int N, int E, int GB, int HB) {
    __shared__ int h[1024];
    const int bid = blockIdx.x;

    if (bid >= GB) {                            // ---- histogram role ----
        const int t = threadIdx.x;
        for (int i = t; i < 1024; i += 256) h[i] = 0;
        __syncthreads();
        const int hb = bid - GB;
        const int n4 = E >> 2;
        for (int i = hb * 256 + t; i < n4; i += HB * 256) {
            int4 d4 = reinterpret_cast<const int4*>(edst)[i];
            atomicAdd(&h[d4.x >> 7], 1);
            atomicAdd(&h[d4.y >> 7], 1);
            atomicAdd(&h[d4.z >> 7], 1);
            atomicAdd(&h[d4.w >> 7], 1);
        }
        if (hb == 0)
            for (int e = (n4 << 2) + t; e < E; e += 256)
                atomicAdd(&h[edst[e] >> 7], 1);
        __syncthreads();
        for (int i = t; i < 1024; i += 256)
            if (h[i]) atomicAdd(&cnt[i], h[i]);
        return;
    }

    // ---- GEMM role: xw[N,64] = x @ W via bf16 MFMA, split precision ----
    // All 32 x float4 loads issued up front (128 VGPRs, compile-time
    // indexed) for maximal memory-level parallelism; frag loads are
    // L1/L2-hot and interleave with MFMA in the fully unrolled kt loop.
    const int lane = threadIdx.x & 63;
    const int wave = threadIdx.x >> 6;
    const int rowbase = (bid * 4 + wave) * 32;
    if (rowbase >= N) return;
    const int rlo = lane & 15;
    const int khi = lane >> 4;

    int row0 = rowbase + rlo;            // t=0 row for this lane
    int row1 = rowbase + 16 + rlo;       // t=1 row
    if (row0 > N - 1) row0 = N - 1;      // clamp (last block only)
    if (row1 > N - 1) row1 = N - 1;
    const float4* xp0 = reinterpret_cast<const float4*>(
        x + (size_t)row0 * IN_DIM + khi * 8);
    const float4* xp1 = reinterpret_cast<const float4*>(
        x + (size_t)row1 * IN_DIM + khi * 8);

    float4 xa[8][2], xb[8][2];
#pragma unroll
    for (int kt = 0; kt < 8; ++kt) {
        xa[kt][0] = xp0[kt * 8 + 0];     // kt*32 floats = kt*8 float4
        xa[kt][1] = xp0[kt * 8 + 1];
        xb[kt][0] = xp1[kt * 8 + 0];
        xb[kt][1] = xp1[kt * 8 + 1];
    }

    f32x4 acc[2][4];
#pragma unroll
    for (int t = 0; t < 2; ++t)
#pragma unroll
        for (int nt = 0; nt < 4; ++nt) acc[t][nt] = (f32x4){0.f, 0.f, 0.f, 0.f};

#pragma unroll
    for (int kt = 0; kt < 8; ++kt) {
        bf16x8 bh[4], bl[4];
#pragma unroll
        for (int nt = 0; nt < 4; ++nt) {
            bh[nt] = fragH[(kt * 4 + nt) * 64 + lane];
            bl[nt] = fragL[(kt * 4 + nt) * 64 + lane];
        }
        float f0[8] = {xa[kt][0].x, xa[kt][0].y, xa[kt][0].z, xa[kt][0].w,
                       xa[kt][1].x, xa[kt][1].y, xa[kt][1].z, xa[kt][1].w};
        float f1[8] = {xb[kt][0].x, xb[kt][0].y, xb[kt][0].z, xb[kt][0].w,
                       xb[kt][1].x, xb[kt][1].y, xb[kt][1].z, xb[kt][1].w};
        bf16x8 ah0, al0, ah1, al1;
#pragma unroll
        for (int j = 0; j < 8; ++j) {
            unsigned u0 = __float_as_uint(f0[j]);
            ah0[j] = (short)(u0 >> 16);
            float r0 = f0[j] - __uint_as_float(u0 & 0xFFFF0000u);
            al0[j] = (short)(__float_as_uint(r0) >> 16);
            unsigned u1 = __float_as_uint(f1[j]);
            ah1[j] = (short)(u1 >> 16);
            float r1 = f1[j] - __uint_as_float(u1 & 0xFFFF0000u);
            al1[j] = (short)(__float_as_uint(r1) >> 16);
        }
#pragma unroll
        for (int nt = 0; nt < 4; ++nt) {
            acc[0][nt] = __builtin_amdgcn_mfma_f32_16x16x32_bf16(
                ah0, bh[nt], acc[0][nt], 0, 0, 0);
            acc[0][nt] = __builtin_amdgcn_mfma_f32_16x16x32_bf16(
                ah0, bl[nt], acc[0][nt], 0, 0, 0);
            acc[0][nt] = __builtin_amdgcn_mfma_f32_16x16x32_bf16(
                al0, bh[nt], acc[0][nt], 0, 0, 0);
            acc[1][nt] = __builtin_amdgcn_mfma_f32_16x16x32_bf16(
                ah1, bh[nt], acc[1][nt], 0, 0, 0);
            acc[1][nt] = __builtin_amdgcn_mfma_f32_16x16x32_bf16(
                ah1, bl[nt], acc[1][nt], 0, 0, 0);
            acc[1][nt] = __builtin_amdgcn_mfma_f32_16x16x32_bf16(
                al1, bh[nt], acc[1][nt], 0, 0, 0);
        }
    }

#pragma unroll
    for (int t = 0; t < 2; ++t)
#pragma unroll
        for (int nt = 0; nt < 4; ++nt)
#pragma unroll
            for (int i = 0; i < 4; ++i) {
                int row = rowbase + t * 16 + khi * 4 + i;
                int col = nt * 16 + rlo;
                if (row < N) {
                    unsigned u = __float_as_uint(acc[t][nt][i]);
                    u += 0x7fffu + ((u >> 16) & 1u);
                    xw[(size_t)row * OUT_DIM + col] = (unsigned short)(u >> 16);
                }
            }
}

// ---- exclusive scan of NB (<=1024) bucket counts, one block ----------------
__global__ __launch_bounds__(1024) void scanb_k(const int* __restrict__ cnt,
                                                int* __restrict__ base,
                                                int* __restrict__ cursor,
                                                int NB, int E) {
    __shared__ int s[1024];
    int t = threadIdx.x;
    int v = (t < NB) ? cnt[t] : 0;
    s[t] = v;
    __syncthreads();
#pragma unroll
    for (int o = 1; o < 1024; o <<= 1) {
        int a = (t >= o) ? s[t - o] : 0;
        __syncthreads();
        s[t] += a;
        __syncthreads();
    }
    if (t < NB) { base[t] = s[t] - v; cursor[t] = s[t] - v; }
    if (t == 0) base[NB] = E;
}

// ---- partition: rec[] grouped by bucket; per-block range reservation -------
// rec = { src | (dst&127)<<17 , bits(w) }   (requires N < 2^17)
// br pack: b(10b) << 19 | dlow(7b) << 12 | rank(12b)
__global__ __launch_bounds__(256) void part_k(const int* __restrict__ esrc,
                                              const int* __restrict__ edst,
                                              const float* __restrict__ ew,
                                              int* __restrict__ cursor,
                                              int2* __restrict__ rec,
                                              int E, int NB) {
    __shared__ int h[1024];
    __shared__ int bb[1024];
    int t = threadIdx.x;
#pragma unroll
    for (int i = t; i < 1024; i += 256) h[i] = 0;
    __syncthreads();
    const int e0 = blockIdx.x * (256 * IPT);
    int br[IPT];
#pragma unroll
    for (int i = 0; i < IPT; ++i) {
        int e = e0 + i * 256 + t;
        br[i] = -1;
        if (e < E) {
            int d = edst[e];
            int b = d >> 7;
            int r = atomicAdd(&h[b], 1);     // local rank, < 4096
            br[i] = (b << 19) | ((d & 127) << 12) | r;
        }
    }
    __syncthreads();
    for (int i = t; i < NB; i += 256) {
        int c = h[i];
        bb[i] = c ? atomicAdd(&cursor[i], c) : 0;
    }
    __syncthreads();
#pragma unroll
    for (int i = 0; i < IPT; ++i) {
        if (br[i] >= 0) {
            int e = e0 + i * 256 + t;
            int b = br[i] >> 19;
            int dlow = (br[i] >> 12) & 127;
            int r = br[i] & 0xFFF;
            rec[bb[b] + r] = make_int2(esrc[e] | (dlow << 17),
                                       __float_as_int(ew[e]));
        }
    }
}

// ---- finalize: per-bucket counting sort -> node-ordered val[] + CSR off[] --
__global__ __launch_bounds__(256) void finalize_k(const int2* __restrict__ rec,
                                                  const int* __restrict__ base,
                                                  int2* __restrict__ val,
                                                  int* __restrict__ off,
                                                  int N, int NB) {
    __shared__ int cnt[NPB];
    __shared__ int sc[NPB];
    __shared__ int cur[NPB];
    const int t = threadIdx.x;
    const int b = blockIdx.x;
    const int s = base[b], e = base[b + 1];

    if (t < NPB) cnt[t] = 0;
    __syncthreads();
    for (int i = s + t; i < e; i += 256)
        atomicAdd(&cnt[(rec[i].x >> 17) & 127], 1);
    __syncthreads();

    if (t < NPB) sc[t] = cnt[t];
    __syncthreads();
#pragma unroll
    for (int o = 1; o < NPB; o <<= 1) {
        int a = 0;
        if (t < NPB && t >= o) a = sc[t - o];
        __syncthreads();
        if (t < NPB) sc[t] += a;
        __syncthreads();
    }
    if (t < NPB) {
        int excl = sc[t] - cnt[t];
        cur[t] = excl;
        int node = b * NPB + t;
        if (node < N) off[node] = s + excl;
    }
    if (b == NB - 1 && t == 0) off[N] = e;
    __syncthreads();

    for (int i = s + t; i < e; i += 256) {
        int2 r = rec[i];
        int dl = (r.x >> 17) & 127;
        int slot = s + atomicAdd(&cur[dl], 1);
        val[slot] = make_int2(r.x & 0x1FFFF, r.y);
    }
}

// ---- gather v3: wave = 1 node, 16 edges in flight --------------------------
__global__ __launch_bounds__(256) void gather_k(const unsigned short* __restrict__ xw,
                                                const int2* __restrict__ val,
                                                const int* __restrict__ off,
                                                float* __restrict__ out, int N) {
    int d = blockIdx.x * 4 + (threadIdx.x >> 6);
    if (d >= N) return;
    const int lane = threadIdx.x & 63;
    const int g = lane >> 3, s = lane & 7;
    const int b = off[d], e = off[d + 1];

    float acc[8];
#pragma unroll
    for (int j = 0; j < 8; ++j) acc[j] = 0.f;

    for (int i = b; i < e; i += 16) {
        int idx0 = i + g;
        int idx1 = i + g + 8;
        int2 r0 = val[min(idx0, e - 1)];
        int2 r1 = val[min(idx1, e - 1)];
        float w0 = (idx0 < e) ? __int_as_float(r0.y) : 0.f;
        float w1 = (idx1 < e) ? __int_as_float(r1.y) : 0.f;
        int4 row0 = *reinterpret_cast<const int4*>(
            xw + (size_t)r0.x * OUT_DIM + s * 8);
        int4 row1 = *reinterpret_cast<const int4*>(
            xw + (size_t)r1.x * OUT_DIM + s * 8);
        unsigned a0 = (unsigned)row0.x, a1 = (unsigned)row0.y;
        unsigned a2 = (unsigned)row0.z, a3 = (unsigned)row0.w;
        acc[0] += w0 * __uint_as_float(a0 << 16);
        acc[1] += w0 * __uint_as_float(a0 & 0xFFFF0000u);
        acc[2] += w0 * __uint_as_float(a1 << 16);
        acc[3] += w0 * __uint_as_float(a1 & 0xFFFF0000u);
        acc[4] += w0 * __uint_as_float(a2 << 16);
        acc[5] += w0 * __uint_as_float(a2 & 0xFFFF0000u);
        acc[6] += w0 * __uint_as_float(a3 << 16);
        acc[7] += w0 * __uint_as_float(a3 & 0xFFFF0000u);
        unsigned b0 = (unsigned)row1.x, b1 = (unsigned)row1.y;
        unsigned b2 = (unsigned)row1.z, b3 = (unsigned)row1.w;
        acc[0] += w1 * __uint_as_float(b0 << 16);
        acc[1] += w1 * __uint_as_float(b0 & 0xFFFF0000u);
        acc[2] += w1 * __uint_as_float(b1 << 16);
        acc[3] += w1 * __uint_as_float(b1 & 0xFFFF0000u);
        acc[4] += w1 * __uint_as_float(b2 << 16);
        acc[5] += w1 * __uint_as_float(b2 & 0xFFFF0000u);
        acc[6] += w1 * __uint_as_float(b3 << 16);
        acc[7] += w1 * __uint_as_float(b3 & 0xFFFF0000u);
    }

#pragma unroll
    for (int m = 8; m < 64; m <<= 1)
#pragma unroll
        for (int j = 0; j < 8; ++j)
            acc[j] += __shfl_xor(acc[j], m);

    if (g == 0) {
        float4 v0 = make_float4(fmaxf(acc[0], 0.f), fmaxf(acc[1], 0.f),
                                fmaxf(acc[2], 0.f), fmaxf(acc[3], 0.f));
        float4 v1 = make_float4(fmaxf(acc[4], 0.f), fmaxf(acc[5], 0.f),
                                fmaxf(acc[6], 0.f), fmaxf(acc[7], 0.f));
        float4* op = reinterpret_cast<float4*>(out + (size_t)d * OUT_DIM + s * 8);
        op[0] = v0;
        op[1] = v1;
    }
}

extern "C" void kernel_launch(void* const* d_in, const int* in_sizes, int n_in,
                              void* d_out, int out_size, void* d_ws, size_t ws_size,
                              hipStream_t stream) {
    const float* x    = (const float*)d_in[0];
    const float* W    = (const float*)d_in[1];
    const int*   esrc = (const int*)d_in[2];
    const int*   edst = (const int*)d_in[3];
    const float* ew   = (const float*)d_in[4];
    float* out = (float*)d_out;

    const int N  = in_sizes[0] / IN_DIM;     // 100000
    const int E  = in_sizes[2];              // 1600000
    const int NB = (N + NPB - 1) / NPB;      // 782
    const int GB = (N + 127) / 128;          // gemm blocks = 782
    const int HB = 512;                      // histogram blocks

    char* ws = (char*)d_ws;
    size_t o = 0;
    bf16x8* fragH = (bf16x8*)(ws + o);  o += 32 * 64 * 16;
    bf16x8* fragL = (bf16x8*)(ws + o);  o += 32 * 64 * 16;
    unsigned short* xw = (unsigned short*)(ws + o);
    o += (size_t)N * OUT_DIM * 2;            // 12.8 MB
    int2* rec  = (int2*)(ws + o);       o += (size_t)E * 8;   // 12.8 MB
    int2* val  = (int2*)(ws + o);       o += (size_t)E * 8;   // 12.8 MB
    int* cnt   = (int*)(ws + o);        o += 1024 * 4;
    int* base  = (int*)(ws + o);        o += 1025 * 4;
    int* cursor = (int*)(ws + o);       o += 1024 * 4;
    int* off   = (int*)(ws + o);        o += (size_t)(N + 1) * 4;

    wfrag_k<<<32, 64, 0, stream>>>(W, fragH, fragL, cnt);
    gemm_hist_k<<<GB + HB, 256, 0, stream>>>(x, fragH, fragL, xw, edst, cnt,
                                             N, E, GB, HB);
    scanb_k<<<1, 1024, 0, stream>>>(cnt, base, cursor, NB, E);
    part_k <<<(E + 256 * IPT - 1) / (256 * IPT), 256, 0, stream>>>(
        esrc, edst, ew, cursor, rec, E, NB);
    finalize_k<<<NB, 256, 0, stream>>>(rec, base, val, off, N, NB);
    gather_k<<<(N + 3) / 4, 256, 0, stream>>>(xw, val, off, out, N);
}